// Round 5
// baseline (3573.239 us; speedup 1.0000x reference)
//
#include <hip/hip_runtime.h>
#include <cstdint>

#define B_SZ 256
#define T_SEQ 512
#define I_SZ 256
#define H_SZ 512
#define O_SZ 256

typedef short shortx8 __attribute__((ext_vector_type(8)));
typedef float floatx4 __attribute__((ext_vector_type(4)));
typedef unsigned int uintx4 __attribute__((ext_vector_type(4)));

#define SENT 0xFFFFFFFFu  // bf16 NaN|NaN — unreachable for h in [-1,1]

__device__ __forceinline__ unsigned short f2bf(float f) {
  uint32_t u = __float_as_uint(f);
  u = u + 0x7fffu + ((u >> 16) & 1u);   // RNE
  return (unsigned short)(u >> 16);
}
__device__ __forceinline__ float bf2f(unsigned short h) {
  return __uint_as_float(((uint32_t)h) << 16);
}
__device__ __forceinline__ float sigm(float x) { return 1.0f / (1.0f + __expf(-x)); }
__device__ __forceinline__ float tanh_fast(float x) {
  x = fminf(15.0f, fmaxf(-15.0f, x));
  float e = __expf(2.0f * x);
  return (e - 1.0f) / (e + 1.0f);
}
__device__ __forceinline__ uint32_t umax_(uint32_t a, uint32_t b) {
  return a > b ? a : b;
}
__device__ __forceinline__ uintx4 umax4_(uintx4 a, uintx4 b) {
  uintx4 r;
  r.x = umax_(a.x, b.x); r.y = umax_(a.y, b.y);
  r.z = umax_(a.z, b.z); r.w = umax_(a.w, b.w);
  return r;
}

// ---------------------------------------------------------------------------
// Phase 0: pack weights.
//   whf[cg][w][nt][ks][lane][j]: bf16 MFMA B-frag order, per-WAVE gate-mixed
//   n-tiles: nt0 = [f cols(8) | g cols(8)], nt1 = [i cols(8) | o cols(8)],
//   hidden col = cg*32 + w*8 + (n&7), k = ks*32 + (lane>>4)*8 + j.
// ---------------------------------------------------------------------------
__global__ __launch_bounds__(256) void pack_kernel(
    const float* __restrict__ Wf, const float* __restrict__ Wi,
    const float* __restrict__ Wc, const float* __restrict__ Wo,
    const float* __restrict__ bf, const float* __restrict__ bi,
    const float* __restrict__ bc, const float* __restrict__ bo,
    unsigned short* __restrict__ whf, unsigned short* __restrict__ wx,
    float* __restrict__ bias) {
  int idx = blockIdx.x * 256 + threadIdx.x;
  if (idx < 2048) {
    int g = idx >> 9, hid = idx & 511;
    const float* bp = (g == 0) ? bf : (g == 1) ? bi : (g == 2) ? bc : bo;
    bias[idx] = bp[hid];
  }
  int i2 = idx - 2048;
  if (i2 >= 0 && i2 < 256 * 2048) {
    int k = i2 >> 11, col = i2 & 2047, g = col >> 9, hid = col & 511;
    const float* Wp = (g == 0) ? Wf : (g == 1) ? Wi : (g == 2) ? Wc : Wo;
    wx[i2] = f2bf(Wp[k * 512 + hid]);
  }
  int i3 = i2 - 256 * 2048;
  if (i3 >= 0 && i3 < 1048576) {
    int j = i3 & 7, l = (i3 >> 3) & 63, ks = (i3 >> 9) & 15;
    int nt = (i3 >> 13) & 1, w = (i3 >> 14) & 3, cg = (i3 >> 16) & 15;
    int k = ks * 32 + (l >> 4) * 8 + j;
    int n = l & 15;
    int hid = cg * 32 + w * 8 + (n & 7);
    int g = (nt == 0) ? ((n < 8) ? 0 : 2) : ((n < 8) ? 1 : 3);
    const float* Wp = (g == 0) ? Wf : (g == 1) ? Wi : (g == 2) ? Wc : Wo;
    whf[i3] = f2bf(Wp[(256 + k) * 512 + hid]);
  }
}

// Init: h slot 0 = zeros (h0), c state = zeros.
__global__ __launch_bounds__(256) void init_kernel(uint32_t* h_ex, float* c_gl) {
  int idx = blockIdx.x * 256 + threadIdx.x;
  if (idx < 65536) h_ex[idx] = 0u;
  if (idx < 131072) c_gl[idx] = 0.0f;
}

// Poison: sentinel-fill all TCp1 slots EXCEPT the live one.
__global__ __launch_bounds__(256) void poison_kernel(uint32_t* h_ex, int live,
                                                     int TCp1) {
  size_t idx = (size_t)blockIdx.x * 256 + threadIdx.x;
  if (idx >= (size_t)TCp1 * 16384) return;
  int slot = (int)(idx >> 14);
  if (slot == live) return;
  ((uint4*)h_ex)[idx] = make_uint4(SENT, SENT, SENT, SENT);
}

// ---------------------------------------------------------------------------
// Phase 1: Z = X @ Wx + bias (bf16 out, [row][gate*512+hid]). Unchanged.
// ---------------------------------------------------------------------------
__global__ __launch_bounds__(256) void gemm_x(
    const float* __restrict__ X, const unsigned short* __restrict__ Wx,
    const float* __restrict__ bias, unsigned short* __restrict__ Z,
    int t0, int TC, int tcs) {
  __shared__ unsigned short lds_a[128 * 72];
  __shared__ unsigned short lds_b[128 * 72];
  const int tid = threadIdx.x;
  const int mt = blockIdx.x >> 4, ntb = blockIdx.x & 15;
  const int n0 = ntb * 128;
  const int w = tid >> 6, l = tid & 63, q = l >> 4, n15 = l & 15;

  floatx4 acc[2][8];
#pragma unroll
  for (int a = 0; a < 2; ++a)
#pragma unroll
    for (int nb = 0; nb < 8; ++nb) acc[a][nb] = (floatx4){0.f, 0.f, 0.f, 0.f};

  const int i_row = tid >> 1, half = tid & 1;
  const int Mr = mt * 128 + i_row;
  const int bb = Mr >> tcs, tt = Mr & (TC - 1);
  const float* asrc = X + ((size_t)(bb * T_SEQ + t0 + tt)) * I_SZ;

  for (int ko = 0; ko < 4; ++ko) {
    const int k0 = ko * 64;
    __syncthreads();
#pragma unroll
    for (int u = 0; u < 8; ++u) {
      int kl = half * 32 + u * 4;
      float4 v = *(const float4*)(asrc + k0 + kl);
      uint2 pk;
      pk.x = (uint32_t)f2bf(v.x) | ((uint32_t)f2bf(v.y) << 16);
      pk.y = (uint32_t)f2bf(v.z) | ((uint32_t)f2bf(v.w) << 16);
      *(uint2*)(lds_a + i_row * 72 + kl) = pk;
    }
    {
      int kb = tid >> 4, n8 = (tid & 15) * 8;
#pragma unroll
      for (int p = 0; p < 4; ++p) {
        int kl = p * 16 + kb;
        const unsigned short* srcw = Wx + (size_t)(k0 + kl) * 2048 + n0 + n8;
        uint4 v = *(const uint4*)srcw;
        unsigned short* db = lds_b + kl;
        db[(n8 + 0) * 72] = (unsigned short)(v.x & 0xffff);
        db[(n8 + 1) * 72] = (unsigned short)(v.x >> 16);
        db[(n8 + 2) * 72] = (unsigned short)(v.y & 0xffff);
        db[(n8 + 3) * 72] = (unsigned short)(v.y >> 16);
        db[(n8 + 4) * 72] = (unsigned short)(v.z & 0xffff);
        db[(n8 + 5) * 72] = (unsigned short)(v.z >> 16);
        db[(n8 + 6) * 72] = (unsigned short)(v.w & 0xffff);
        db[(n8 + 7) * 72] = (unsigned short)(v.w >> 16);
      }
    }
    __syncthreads();
#pragma unroll
    for (int kk = 0; kk < 2; ++kk) {
      shortx8 af[2], bfr[8];
#pragma unroll
      for (int a = 0; a < 2; ++a) {
        int row = (w * 2 + a) * 16 + n15;
        af[a] = *(const shortx8*)(lds_a + row * 72 + kk * 32 + q * 8);
      }
#pragma unroll
      for (int nb = 0; nb < 8; ++nb) {
        int col = nb * 16 + n15;
        bfr[nb] = *(const shortx8*)(lds_b + col * 72 + kk * 32 + q * 8);
      }
#pragma unroll
      for (int a = 0; a < 2; ++a)
#pragma unroll
        for (int nb = 0; nb < 8; ++nb)
          acc[a][nb] = __builtin_amdgcn_mfma_f32_16x16x32_bf16(
              af[a], bfr[nb], acc[a][nb], 0, 0, 0);
    }
  }
#pragma unroll
  for (int a = 0; a < 2; ++a) {
#pragma unroll
    for (int nb = 0; nb < 8; ++nb) {
      int colg = n0 + nb * 16 + n15;
      float bv = bias[colg];
      floatx4 v = acc[a][nb];
#pragma unroll
      for (int r = 0; r < 4; ++r) {
        int Mrow = mt * 128 + (w * 2 + a) * 16 + q * 4 + r;
        Z[(size_t)Mrow * 2048 + colg] = f2bf(v[r] + bv);
      }
    }
  }
}

// ---------------------------------------------------------------------------
// Phase 2: recurrent chunk — BARRIER-FREE. Wave w owns 8 hidden cols
// (cg*32+w*8..+8) for all 4 gates; f/i in lanes n15<8, g/o in lanes n15>=8
// of the SAME wave -> shfl_xor exchange, no LDS, no __syncthreads in loop.
// Data-rail sentinel poll (dword-atomic h stores). Consumer wave q pairs
// with producer wave w=q.
// ---------------------------------------------------------------------------
__global__ __launch_bounds__(256, 1) void lstm_chunk(
    const unsigned short* __restrict__ Z, const unsigned short* __restrict__ whf,
    uint32_t* h_ex, float* c_gl, int t0, int TC) {
  __shared__ unsigned short wlds[65536];   // 128 KiB weight panel
  const int tid = threadIdx.x, l = tid & 63, w = tid >> 6, q = l >> 4,
            n15 = l & 15;
  const int bg = blockIdx.x & 15, cg = blockIdx.x >> 4;

  {  // one-time: copy this block's contiguous 128 KiB panel into LDS
    const uint4* src = (const uint4*)(whf + (size_t)cg * 65536);
    uint4* dst = (uint4*)wlds;
#pragma unroll
    for (int i = 0; i < 32; ++i) dst[i * 256 + tid] = src[i * 256 + tid];
  }
  __builtin_amdgcn_fence(__ATOMIC_ACQUIRE, "");  // once per dispatch
  __syncthreads();                                // weights ready (only barrier)

  // c-state: lanes n15<8 own rows q*4..+3 of hidden col cg*32+w*8+n15
  const int myhid = cg * 32 + w * 8 + (n15 & 7);
  float cs[4] = {0.f, 0.f, 0.f, 0.f};
  if (n15 < 8) {
#pragma unroll
    for (int r = 0; r < 4; ++r)
      cs[r] = c_gl[(bg * 16 + q * 4 + r) * 512 + myhid];
  }

  const unsigned short* wb0 = wlds + w * 16384;  // nt0: [ks][lane][8]
  const unsigned short* wb1 = wb0 + 8192;        // nt1
  const int TCp1 = TC + 1;
  int sr = t0 % TCp1;  // read slot for step t

  const size_t afoff = ((size_t)(bg * 64 + q) * 16 + n15) * 8;  // shorts
  const int g0col = ((n15 < 8) ? 0 : 2) * 512 + myhid;  // f / g
  const int g1col = ((n15 < 8) ? 1 : 3) * 512 + myhid;  // i / o

  for (int t = t0; t < t0 + TC; ++t) {
    int sw = sr + 1;
    if (sw == TCp1) sw = 0;
    // Z prefetch (cached; issued before the poll)
    float zv0[4], zv1[4];
#pragma unroll
    for (int r = 0; r < 4; ++r) {
      size_t rowoff = ((size_t)(bg * 16 + q * 4 + r) * TC + (t - t0)) * 2048;
      zv0[r] = bf2f(Z[rowoff + g0col]);
      zv1[r] = bf2f(Z[rowoff + g1col]);
    }
    // B prefetch ks 0..7 (LDS; overlaps the poll)
    shortx8 bp0[8], bp1[8];
#pragma unroll
    for (int ks = 0; ks < 8; ++ks) {
      bp0[ks] = *(const shortx8*)(wb0 + ks * 512 + l * 8);
      bp1[ks] = *(const shortx8*)(wb1 + ks * 512 + l * 8);
    }

    // ---- data-rail poll: 16x dwordx4 system loads until no SENT dword ----
    const unsigned short* pa =
        (const unsigned short*)(h_ex + (size_t)sr * 65536) + afoff;
    uintx4 A0, A1, A2, A3, A4, A5, A6, A7, A8, A9, A10, A11, A12, A13, A14, A15;
    uint32_t mx;
    do {
      asm volatile(
          "global_load_dwordx4 %0, %16, off sc0 sc1\n\t"
          "global_load_dwordx4 %1, %16, off offset:1024 sc0 sc1\n\t"
          "global_load_dwordx4 %2, %16, off offset:2048 sc0 sc1\n\t"
          "global_load_dwordx4 %3, %16, off offset:3072 sc0 sc1\n\t"
          "global_load_dwordx4 %4, %17, off sc0 sc1\n\t"
          "global_load_dwordx4 %5, %17, off offset:1024 sc0 sc1\n\t"
          "global_load_dwordx4 %6, %17, off offset:2048 sc0 sc1\n\t"
          "global_load_dwordx4 %7, %17, off offset:3072 sc0 sc1\n\t"
          "global_load_dwordx4 %8, %18, off sc0 sc1\n\t"
          "global_load_dwordx4 %9, %18, off offset:1024 sc0 sc1\n\t"
          "global_load_dwordx4 %10, %18, off offset:2048 sc0 sc1\n\t"
          "global_load_dwordx4 %11, %18, off offset:3072 sc0 sc1\n\t"
          "global_load_dwordx4 %12, %19, off sc0 sc1\n\t"
          "global_load_dwordx4 %13, %19, off offset:1024 sc0 sc1\n\t"
          "global_load_dwordx4 %14, %19, off offset:2048 sc0 sc1\n\t"
          "global_load_dwordx4 %15, %19, off offset:3072 sc0 sc1\n\t"
          "s_waitcnt vmcnt(0)"
          : "=&v"(A0), "=&v"(A1), "=&v"(A2), "=&v"(A3), "=&v"(A4), "=&v"(A5),
            "=&v"(A6), "=&v"(A7), "=&v"(A8), "=&v"(A9), "=&v"(A10), "=&v"(A11),
            "=&v"(A12), "=&v"(A13), "=&v"(A14), "=&v"(A15)
          : "v"(pa), "v"(pa + 2048), "v"(pa + 4096), "v"(pa + 6144)
          : "memory");
      uintx4 m = umax4_(umax4_(umax4_(A0, A1), umax4_(A2, A3)),
                        umax4_(umax4_(A4, A5), umax4_(A6, A7)));
      m = umax4_(m, umax4_(umax4_(A8, A9), umax4_(A10, A11)));
      m = umax4_(m, umax4_(umax4_(A12, A13), umax4_(A14, A15)));
      mx = umax_(umax_(m.x, m.y), umax_(m.z, m.w));
    } while (__any(mx == SENT));

    uintx4 Au[16] = {A0, A1, A2,  A3,  A4,  A5,  A6,  A7,
                     A8, A9, A10, A11, A12, A13, A14, A15};
    floatx4 a0 = (floatx4){0.f, 0.f, 0.f, 0.f};
    floatx4 a1 = (floatx4){0.f, 0.f, 0.f, 0.f};
#pragma unroll
    for (int ks = 0; ks < 8; ++ks) {
      shortx8 af = *(shortx8*)&Au[ks];
      a0 = __builtin_amdgcn_mfma_f32_16x16x32_bf16(af, bp0[ks], a0, 0, 0, 0);
      a1 = __builtin_amdgcn_mfma_f32_16x16x32_bf16(af, bp1[ks], a1, 0, 0, 0);
    }
#pragma unroll
    for (int ks = 8; ks < 16; ++ks) {
      shortx8 af = *(shortx8*)&Au[ks];
      shortx8 tb0 = *(const shortx8*)(wb0 + ks * 512 + l * 8);
      shortx8 tb1 = *(const shortx8*)(wb1 + ks * 512 + l * 8);
      a0 = __builtin_amdgcn_mfma_f32_16x16x32_bf16(af, tb0, a0, 0, 0, 0);
      a1 = __builtin_amdgcn_mfma_f32_16x16x32_bf16(af, tb1, a1, 0, 0, 0);
    }
    // gates: lanes n15<8: a0=f(sigm), a1=i(sigm); lanes>=8: a0=g(tanh), a1=o(sigm)
    float gv0[4], gv1[4];
#pragma unroll
    for (int r = 0; r < 4; ++r) {
      float x0 = a0[r] + zv0[r];
      float x1 = a1[r] + zv1[r];
      gv0[r] = (n15 < 8) ? sigm(x0) : tanh_fast(x0);
      gv1[r] = sigm(x1);
    }
    // intra-wave exchange + c/h update (meaningful in lanes n15<8)
    uint32_t packs[4];
#pragma unroll
    for (int r = 0; r < 4; ++r) {
      float gp = __shfl_xor(gv0[r], 8, 64);  // g for lanes<8
      float op = __shfl_xor(gv1[r], 8, 64);  // o for lanes<8
      float cn = gv0[r] * cs[r] + gv1[r] * gp;
      cs[r] = cn;
      float h = op * tanh_fast(cn);
      uint32_t hs = (uint32_t)f2bf(h);
      uint32_t prt = __shfl_xor(hs, 1, 64);
      packs[r] = (n15 & 1) ? (prt | (hs << 16)) : (hs | (prt << 16));
    }
    if (n15 < 8) {
      // dword idx within slot: ((bg*16+cg)*4+w)*64 + m*4 + n15/2, m=q*4+r
      size_t base = (size_t)sw * 65536 +
                    ((size_t)(bg * 16 + cg) * 4 + w) * 64 + (n15 >> 1);
      int r0 = (n15 & 1) ? 2 : 0;  // even lane stores r=0,1; odd r=2,3
#pragma unroll
      for (int rr = 0; rr < 2; ++rr) {
        int r = r0 + rr;
        __hip_atomic_store(h_ex + base + (size_t)(q * 4 + r) * 4, packs[r],
                           __ATOMIC_RELAXED, __HIP_MEMORY_SCOPE_SYSTEM);
      }
    }
    sr = sw;
  }
  if (n15 < 8) {
#pragma unroll
    for (int r = 0; r < 4; ++r)
      c_gl[(bg * 16 + q * 4 + r) * 512 + myhid] = cs[r];
  }
}

// ---------------------------------------------------------------------------
// Phase 3: logits + log_softmax (reads final h slot, new layout).
// ---------------------------------------------------------------------------
__global__ __launch_bounds__(256) void out_kernel(
    const uint32_t* __restrict__ hfin, const float* __restrict__ Wout,
    const float* __restrict__ bout, float* __restrict__ out) {
  const int b = blockIdx.x, tid = threadIdx.x;
  __shared__ float hrow[512];
  if (tid < 64) {
    int cg = tid >> 2, w = tid & 3;
    const unsigned short* hp =
        (const unsigned short*)hfin +
        (((size_t)(b >> 4) * 16 + cg) * 4 + w) * 128 + (size_t)(b & 15) * 8;
    uint4 v = *(const uint4*)hp;
    uint32_t u[4] = {v.x, v.y, v.z, v.w};
#pragma unroll
    for (int d = 0; d < 4; ++d) {
      hrow[cg * 32 + w * 8 + d * 2] = bf2f((unsigned short)(u[d] & 0xffff));
      hrow[cg * 32 + w * 8 + d * 2 + 1] = bf2f((unsigned short)(u[d] >> 16));
    }
  }
  __syncthreads();
  float acc = bout[tid];
  for (int k = 0; k < 512; ++k) acc += hrow[k] * Wout[k * 256 + tid];
  __shared__ float red[256];
  red[tid] = acc;
  __syncthreads();
  for (int s = 128; s > 0; s >>= 1) {
    if (tid < s) red[tid] = fmaxf(red[tid], red[tid + s]);
    __syncthreads();
  }
  float mx = red[0];
  __syncthreads();
  red[tid] = __expf(acc - mx);
  __syncthreads();
  for (int s = 128; s > 0; s >>= 1) {
    if (tid < s) red[tid] += red[tid + s];
    __syncthreads();
  }
  out[b * 256 + tid] = acc - mx - logf(red[0]);
}

// ---------------------------------------------------------------------------
extern "C" void kernel_launch(void* const* d_in, const int* in_sizes, int n_in,
                              void* d_out, int out_size, void* d_ws,
                              size_t ws_size, hipStream_t stream) {
  const float* X = (const float*)d_in[0];
  const float* Wf = (const float*)d_in[1];
  const float* bf = (const float*)d_in[2];
  const float* Wi = (const float*)d_in[3];
  const float* bi = (const float*)d_in[4];
  const float* Wc = (const float*)d_in[5];
  const float* bc = (const float*)d_in[6];
  const float* Wo = (const float*)d_in[7];
  const float* bo = (const float*)d_in[8];
  const float* Wout = (const float*)d_in[9];
  const float* bout = (const float*)d_in[10];

  char* ws = (char*)d_ws;
  unsigned short* whf = (unsigned short*)(ws + 0x000000);   // 2 MiB
  unsigned short* wxb = (unsigned short*)(ws + 0x200000);   // 1 MiB
  float* bias = (float*)(ws + 0x300000);                    // 8 KiB
  float* c_gl = (float*)(ws + 0x310000);                    // 512 KiB
  uint32_t* h_ex = (uint32_t*)(ws + 0x400000);              // 257 x 256 KiB
  const size_t zoff = 0x4500000;                            // 69 MiB
  unsigned short* Z = (unsigned short*)(ws + zoff);         // TC MiB

  int TC = 256;
  while (TC > 16 && zoff + ((size_t)B_SZ * TC * 2048 * 2) > ws_size) TC >>= 1;
  int tcs = 0;
  while ((1 << tcs) < TC) ++tcs;
  const int TCp1 = TC + 1;

  pack_kernel<<<(2048 + 256 * 2048 + 1048576 + 255) / 256, 256, 0, stream>>>(
      Wf, Wi, Wc, Wo, bf, bi, bc, bo, whf, wxb, bias);
  init_kernel<<<512, 256, 0, stream>>>(h_ex, c_gl);

  for (int t0 = 0; t0 < T_SEQ; t0 += TC) {
    poison_kernel<<<(TCp1 * 16384 + 255) / 256, 256, 0, stream>>>(
        h_ex, t0 % TCp1, TCp1);
    gemm_x<<<(B_SZ * TC / 128) * 16, 256, 0, stream>>>(X, wxb, bias, Z, t0, TC,
                                                       tcs);
    lstm_chunk<<<256, 256, 0, stream>>>(Z, whf, h_ex, c_gl, t0, TC);
  }
  const int sfin = T_SEQ % TCp1;
  out_kernel<<<256, 256, 0, stream>>>(h_ex + (size_t)sfin * 65536, Wout, bout,
                                      (float*)d_out);
}

// Round 6
// 2753.876 us; speedup vs baseline: 1.2975x; 1.2975x over previous
//
#include <hip/hip_runtime.h>
#include <cstdint>

#define B_SZ 256
#define T_SEQ 512
#define I_SZ 256
#define H_SZ 512
#define O_SZ 256

typedef short shortx8 __attribute__((ext_vector_type(8)));
typedef float floatx4 __attribute__((ext_vector_type(4)));
typedef unsigned int uintx4 __attribute__((ext_vector_type(4)));

#define SENT 0xFFFFFFFFu  // bf16 NaN|NaN — unreachable for h in [-1,1]

__device__ __forceinline__ unsigned short f2bf(float f) {
  uint32_t u = __float_as_uint(f);
  u = u + 0x7fffu + ((u >> 16) & 1u);   // RNE
  return (unsigned short)(u >> 16);
}
__device__ __forceinline__ float bf2f(unsigned short h) {
  return __uint_as_float(((uint32_t)h) << 16);
}
__device__ __forceinline__ float sigm(float x) { return 1.0f / (1.0f + __expf(-x)); }
__device__ __forceinline__ float tanh_fast(float x) {
  x = fminf(15.0f, fmaxf(-15.0f, x));
  float e = __expf(2.0f * x);
  return (e - 1.0f) / (e + 1.0f);
}
__device__ __forceinline__ uint32_t umax_(uint32_t a, uint32_t b) {
  return a > b ? a : b;
}
__device__ __forceinline__ uintx4 umax4_(uintx4 a, uintx4 b) {
  uintx4 r;
  r.x = umax_(a.x, b.x); r.y = umax_(a.y, b.y);
  r.z = umax_(a.z, b.z); r.w = umax_(a.w, b.w);
  return r;
}

// ---------------------------------------------------------------------------
// Phase 0: pack weights (unchanged from round 5; per-wave gate-mixed n-tiles).
// ---------------------------------------------------------------------------
__global__ __launch_bounds__(256) void pack_kernel(
    const float* __restrict__ Wf, const float* __restrict__ Wi,
    const float* __restrict__ Wc, const float* __restrict__ Wo,
    const float* __restrict__ bf, const float* __restrict__ bi,
    const float* __restrict__ bc, const float* __restrict__ bo,
    unsigned short* __restrict__ whf, unsigned short* __restrict__ wx,
    float* __restrict__ bias) {
  int idx = blockIdx.x * 256 + threadIdx.x;
  if (idx < 2048) {
    int g = idx >> 9, hid = idx & 511;
    const float* bp = (g == 0) ? bf : (g == 1) ? bi : (g == 2) ? bc : bo;
    bias[idx] = bp[hid];
  }
  int i2 = idx - 2048;
  if (i2 >= 0 && i2 < 256 * 2048) {
    int k = i2 >> 11, col = i2 & 2047, g = col >> 9, hid = col & 511;
    const float* Wp = (g == 0) ? Wf : (g == 1) ? Wi : (g == 2) ? Wc : Wo;
    wx[i2] = f2bf(Wp[k * 512 + hid]);
  }
  int i3 = i2 - 256 * 2048;
  if (i3 >= 0 && i3 < 1048576) {
    int j = i3 & 7, l = (i3 >> 3) & 63, ks = (i3 >> 9) & 15;
    int nt = (i3 >> 13) & 1, w = (i3 >> 14) & 3, cg = (i3 >> 16) & 15;
    int k = ks * 32 + (l >> 4) * 8 + j;
    int n = l & 15;
    int hid = cg * 32 + w * 8 + (n & 7);
    int g = (nt == 0) ? ((n < 8) ? 0 : 2) : ((n < 8) ? 1 : 3);
    const float* Wp = (g == 0) ? Wf : (g == 1) ? Wi : (g == 2) ? Wc : Wo;
    whf[i3] = f2bf(Wp[(256 + k) * 512 + hid]);
  }
}

// Init: h slot 0 = zeros (h0), c state = zeros.
__global__ __launch_bounds__(256) void init_kernel(uint32_t* h_ex, float* c_gl) {
  int idx = blockIdx.x * 256 + threadIdx.x;
  if (idx < 65536) h_ex[idx] = 0u;
  if (idx < 131072) c_gl[idx] = 0.0f;
}

// Poison: sentinel-fill all TCp1 slots EXCEPT the live one.
__global__ __launch_bounds__(256) void poison_kernel(uint32_t* h_ex, int live,
                                                     int TCp1) {
  size_t idx = (size_t)blockIdx.x * 256 + threadIdx.x;
  if (idx >= (size_t)TCp1 * 16384) return;
  int slot = (int)(idx >> 14);
  if (slot == live) return;
  ((uint4*)h_ex)[idx] = make_uint4(SENT, SENT, SENT, SENT);
}

// ---------------------------------------------------------------------------
// Phase 1: Z = X @ Wx + bias (bf16 out, [row][gate*512+hid]). Unchanged.
// ---------------------------------------------------------------------------
__global__ __launch_bounds__(256) void gemm_x(
    const float* __restrict__ X, const unsigned short* __restrict__ Wx,
    const float* __restrict__ bias, unsigned short* __restrict__ Z,
    int t0, int TC, int tcs) {
  __shared__ unsigned short lds_a[128 * 72];
  __shared__ unsigned short lds_b[128 * 72];
  const int tid = threadIdx.x;
  const int mt = blockIdx.x >> 4, ntb = blockIdx.x & 15;
  const int n0 = ntb * 128;
  const int w = tid >> 6, l = tid & 63, q = l >> 4, n15 = l & 15;

  floatx4 acc[2][8];
#pragma unroll
  for (int a = 0; a < 2; ++a)
#pragma unroll
    for (int nb = 0; nb < 8; ++nb) acc[a][nb] = (floatx4){0.f, 0.f, 0.f, 0.f};

  const int i_row = tid >> 1, half = tid & 1;
  const int Mr = mt * 128 + i_row;
  const int bb = Mr >> tcs, tt = Mr & (TC - 1);
  const float* asrc = X + ((size_t)(bb * T_SEQ + t0 + tt)) * I_SZ;

  for (int ko = 0; ko < 4; ++ko) {
    const int k0 = ko * 64;
    __syncthreads();
#pragma unroll
    for (int u = 0; u < 8; ++u) {
      int kl = half * 32 + u * 4;
      float4 v = *(const float4*)(asrc + k0 + kl);
      uint2 pk;
      pk.x = (uint32_t)f2bf(v.x) | ((uint32_t)f2bf(v.y) << 16);
      pk.y = (uint32_t)f2bf(v.z) | ((uint32_t)f2bf(v.w) << 16);
      *(uint2*)(lds_a + i_row * 72 + kl) = pk;
    }
    {
      int kb = tid >> 4, n8 = (tid & 15) * 8;
#pragma unroll
      for (int p = 0; p < 4; ++p) {
        int kl = p * 16 + kb;
        const unsigned short* srcw = Wx + (size_t)(k0 + kl) * 2048 + n0 + n8;
        uint4 v = *(const uint4*)srcw;
        unsigned short* db = lds_b + kl;
        db[(n8 + 0) * 72] = (unsigned short)(v.x & 0xffff);
        db[(n8 + 1) * 72] = (unsigned short)(v.x >> 16);
        db[(n8 + 2) * 72] = (unsigned short)(v.y & 0xffff);
        db[(n8 + 3) * 72] = (unsigned short)(v.y >> 16);
        db[(n8 + 4) * 72] = (unsigned short)(v.z & 0xffff);
        db[(n8 + 5) * 72] = (unsigned short)(v.z >> 16);
        db[(n8 + 6) * 72] = (unsigned short)(v.w & 0xffff);
        db[(n8 + 7) * 72] = (unsigned short)(v.w >> 16);
      }
    }
    __syncthreads();
#pragma unroll
    for (int kk = 0; kk < 2; ++kk) {
      shortx8 af[2], bfr[8];
#pragma unroll
      for (int a = 0; a < 2; ++a) {
        int row = (w * 2 + a) * 16 + n15;
        af[a] = *(const shortx8*)(lds_a + row * 72 + kk * 32 + q * 8);
      }
#pragma unroll
      for (int nb = 0; nb < 8; ++nb) {
        int col = nb * 16 + n15;
        bfr[nb] = *(const shortx8*)(lds_b + col * 72 + kk * 32 + q * 8);
      }
#pragma unroll
      for (int a = 0; a < 2; ++a)
#pragma unroll
        for (int nb = 0; nb < 8; ++nb)
          acc[a][nb] = __builtin_amdgcn_mfma_f32_16x16x32_bf16(
              af[a], bfr[nb], acc[a][nb], 0, 0, 0);
    }
  }
#pragma unroll
  for (int a = 0; a < 2; ++a) {
#pragma unroll
    for (int nb = 0; nb < 8; ++nb) {
      int colg = n0 + nb * 16 + n15;
      float bv = bias[colg];
      floatx4 v = acc[a][nb];
#pragma unroll
      for (int r = 0; r < 4; ++r) {
        int Mrow = mt * 128 + (w * 2 + a) * 16 + q * 4 + r;
        Z[(size_t)Mrow * 2048 + colg] = f2bf(v[r] + bv);
      }
    }
  }
}

// ---------------------------------------------------------------------------
// Phase 2: recurrent chunk.
//  - Wave 0 polls the 16 KiB h-block (sentinel data-rail, sc0 sc1), then
//    rebroadcasts Af via LDS + release flag; waves 1-3 spin on the LDS flag
//    (poll LIC bandwidth / 4). Single Af buffer is race-free: wave0 can only
//    detect step t+1 after this block's waves stored h(t+1), which requires
//    they finished reading Af(t).
//  - h store: 4 bpermute redistribution -> ALL 64 lanes store 1 contiguous
//    dword (full 64B lines per instruction; kills the R5 partial-line
//    write-allocate traffic).
//  - Barrier-free otherwise; shfl gate exchange; LDS weight panel.
// ---------------------------------------------------------------------------
__global__ __launch_bounds__(256, 1) void lstm_chunk(
    const unsigned short* __restrict__ Z, const unsigned short* __restrict__ whf,
    uint32_t* h_ex, float* c_gl, int t0, int TC) {
  __shared__ unsigned short wlds[65536];   // 128 KiB weight panel
  __shared__ uint32_t afb[4096];           // 16 KiB Af rebroadcast buffer
  __shared__ int afflag;
  const int tid = threadIdx.x, l = tid & 63, w = tid >> 6, q = l >> 4,
            n15 = l & 15;
  const int bg = blockIdx.x & 15, cg = blockIdx.x >> 4;

  {  // one-time: copy this block's contiguous 128 KiB panel into LDS
    const uint4* src = (const uint4*)(whf + (size_t)cg * 65536);
    uint4* dst = (uint4*)wlds;
#pragma unroll
    for (int i = 0; i < 32; ++i) dst[i * 256 + tid] = src[i * 256 + tid];
  }
  if (tid == 0) afflag = t0 - 1;
  __builtin_amdgcn_fence(__ATOMIC_ACQUIRE, "");  // once per dispatch
  __syncthreads();                                // weights+flag ready

  // c-state: lanes n15<8 own rows q*4..+3 of hidden col cg*32+w*8+n15
  const int myhid = cg * 32 + w * 8 + (n15 & 7);
  float cs[4] = {0.f, 0.f, 0.f, 0.f};
  if (n15 < 8) {
#pragma unroll
    for (int r = 0; r < 4; ++r)
      cs[r] = c_gl[(bg * 16 + q * 4 + r) * 512 + myhid];
  }

  const unsigned short* wb0 = wlds + w * 16384;  // nt0: [ks][lane][8]
  const unsigned short* wb1 = wb0 + 8192;        // nt1
  const int TCp1 = TC + 1;
  int sr = t0 % TCp1;  // read slot for step t

  const size_t afoff = ((size_t)(bg * 64 + q) * 16 + n15) * 8;  // shorts
  const int g0col = ((n15 < 8) ? 0 : 2) * 512 + myhid;  // f / g
  const int g1col = ((n15 < 8) ? 1 : 3) * 512 + myhid;  // i / o
  uint32_t* aflane = afb + (q * 16 + n15) * 4;          // LDS Af lane base
  const int slane = (l & 48) + 2 * (n15 & 3);           // bpermute source

  for (int t = t0; t < t0 + TC; ++t) {
    int sw = sr + 1;
    if (sw == TCp1) sw = 0;
    // Z prefetch (cached; issued before the wait)
    float zv0[4], zv1[4];
#pragma unroll
    for (int r = 0; r < 4; ++r) {
      size_t rowoff = ((size_t)(bg * 16 + q * 4 + r) * TC + (t - t0)) * 2048;
      zv0[r] = bf2f(Z[rowoff + g0col]);
      zv1[r] = bf2f(Z[rowoff + g1col]);
    }
    // B prefetch ks 0..7 (LDS; overlaps the wait)
    shortx8 bp0[8], bp1[8];
#pragma unroll
    for (int ks = 0; ks < 8; ++ks) {
      bp0[ks] = *(const shortx8*)(wb0 + ks * 512 + l * 8);
      bp1[ks] = *(const shortx8*)(wb1 + ks * 512 + l * 8);
    }

    uintx4 Au[16];
    if (w == 0) {
      // ---- wave 0: data-rail poll (16x dwordx4 system loads) ----
      const unsigned short* pa =
          (const unsigned short*)(h_ex + (size_t)sr * 65536) + afoff;
      uintx4 A0, A1, A2, A3, A4, A5, A6, A7, A8, A9, A10, A11, A12, A13, A14,
          A15;
      uint32_t mx;
      do {
        asm volatile(
            "global_load_dwordx4 %0, %16, off sc0 sc1\n\t"
            "global_load_dwordx4 %1, %16, off offset:1024 sc0 sc1\n\t"
            "global_load_dwordx4 %2, %16, off offset:2048 sc0 sc1\n\t"
            "global_load_dwordx4 %3, %16, off offset:3072 sc0 sc1\n\t"
            "global_load_dwordx4 %4, %17, off sc0 sc1\n\t"
            "global_load_dwordx4 %5, %17, off offset:1024 sc0 sc1\n\t"
            "global_load_dwordx4 %6, %17, off offset:2048 sc0 sc1\n\t"
            "global_load_dwordx4 %7, %17, off offset:3072 sc0 sc1\n\t"
            "global_load_dwordx4 %8, %18, off sc0 sc1\n\t"
            "global_load_dwordx4 %9, %18, off offset:1024 sc0 sc1\n\t"
            "global_load_dwordx4 %10, %18, off offset:2048 sc0 sc1\n\t"
            "global_load_dwordx4 %11, %18, off offset:3072 sc0 sc1\n\t"
            "global_load_dwordx4 %12, %19, off sc0 sc1\n\t"
            "global_load_dwordx4 %13, %19, off offset:1024 sc0 sc1\n\t"
            "global_load_dwordx4 %14, %19, off offset:2048 sc0 sc1\n\t"
            "global_load_dwordx4 %15, %19, off offset:3072 sc0 sc1\n\t"
            "s_waitcnt vmcnt(0)"
            : "=&v"(A0), "=&v"(A1), "=&v"(A2), "=&v"(A3), "=&v"(A4),
              "=&v"(A5), "=&v"(A6), "=&v"(A7), "=&v"(A8), "=&v"(A9),
              "=&v"(A10), "=&v"(A11), "=&v"(A12), "=&v"(A13), "=&v"(A14),
              "=&v"(A15)
            : "v"(pa), "v"(pa + 2048), "v"(pa + 4096), "v"(pa + 6144)
            : "memory");
        uintx4 m = umax4_(umax4_(umax4_(A0, A1), umax4_(A2, A3)),
                          umax4_(umax4_(A4, A5), umax4_(A6, A7)));
        m = umax4_(m, umax4_(umax4_(A8, A9), umax4_(A10, A11)));
        m = umax4_(m, umax4_(umax4_(A12, A13), umax4_(A14, A15)));
        mx = umax_(umax_(m.x, m.y), umax_(m.z, m.w));
      } while (__any(mx == SENT));
      Au[0] = A0;  Au[1] = A1;  Au[2] = A2;  Au[3] = A3;
      Au[4] = A4;  Au[5] = A5;  Au[6] = A6;  Au[7] = A7;
      Au[8] = A8;  Au[9] = A9;  Au[10] = A10; Au[11] = A11;
      Au[12] = A12; Au[13] = A13; Au[14] = A14; Au[15] = A15;
      // rebroadcast to LDS, then release the flag
#pragma unroll
      for (int ks = 0; ks < 16; ++ks) *(uintx4*)(aflane + ks * 256) = Au[ks];
      __hip_atomic_store(&afflag, t, __ATOMIC_RELEASE,
                         __HIP_MEMORY_SCOPE_WORKGROUP);
    } else {
      // ---- waves 1-3: spin on LDS flag, then read Af from LDS ----
      while (__hip_atomic_load(&afflag, __ATOMIC_ACQUIRE,
                               __HIP_MEMORY_SCOPE_WORKGROUP) < t) {}
#pragma unroll
      for (int ks = 0; ks < 16; ++ks) Au[ks] = *(uintx4*)(aflane + ks * 256);
    }

    floatx4 a0 = (floatx4){0.f, 0.f, 0.f, 0.f};
    floatx4 a1 = (floatx4){0.f, 0.f, 0.f, 0.f};
#pragma unroll
    for (int ks = 0; ks < 8; ++ks) {
      shortx8 af = *(shortx8*)&Au[ks];
      a0 = __builtin_amdgcn_mfma_f32_16x16x32_bf16(af, bp0[ks], a0, 0, 0, 0);
      a1 = __builtin_amdgcn_mfma_f32_16x16x32_bf16(af, bp1[ks], a1, 0, 0, 0);
    }
#pragma unroll
    for (int ks = 8; ks < 16; ++ks) {
      shortx8 af = *(shortx8*)&Au[ks];
      shortx8 tb0 = *(const shortx8*)(wb0 + ks * 512 + l * 8);
      shortx8 tb1 = *(const shortx8*)(wb1 + ks * 512 + l * 8);
      a0 = __builtin_amdgcn_mfma_f32_16x16x32_bf16(af, tb0, a0, 0, 0, 0);
      a1 = __builtin_amdgcn_mfma_f32_16x16x32_bf16(af, tb1, a1, 0, 0, 0);
    }
    // gates: lanes n15<8: a0=f(sigm), a1=i(sigm); lanes>=8: a0=g(tanh), a1=o
    float gv0[4], gv1[4];
#pragma unroll
    for (int r = 0; r < 4; ++r) {
      float x0 = a0[r] + zv0[r];
      float x1 = a1[r] + zv1[r];
      gv0[r] = (n15 < 8) ? sigm(x0) : tanh_fast(x0);
      gv1[r] = sigm(x1);
    }
    // intra-wave exchange + c/h update (meaningful in lanes n15<8)
    uint32_t packs[4];
#pragma unroll
    for (int r = 0; r < 4; ++r) {
      float gp = __shfl_xor(gv0[r], 8, 64);  // g for lanes<8
      float op = __shfl_xor(gv1[r], 8, 64);  // o for lanes<8
      float cn = gv0[r] * cs[r] + gv1[r] * gp;
      cs[r] = cn;
      float h = op * tanh_fast(cn);
      uint32_t hs = (uint32_t)f2bf(h);
      uint32_t prt = __shfl_xor(hs, 1, 64);
      packs[r] = (n15 & 1) ? (prt | (hs << 16)) : (hs | (prt << 16));
    }
    // redistribute so lane (q,n15) holds dword m*4+d (m=q*4+n15>>2, d=n15&3)
    {
      uint32_t t0v = __shfl((int)packs[0], slane, 64);
      uint32_t t1v = __shfl((int)packs[1], slane, 64);
      uint32_t t2v = __shfl((int)packs[2], slane, 64);
      uint32_t t3v = __shfl((int)packs[3], slane, 64);
      int rsel = n15 >> 2;
      uint32_t hv = (rsel == 0) ? t0v : (rsel == 1) ? t1v : (rsel == 2) ? t2v
                                                                        : t3v;
      size_t sbase = (size_t)sw * 65536 +
                     ((size_t)(bg * 16 + cg) * 4 + w) * 64 + q * 16 + n15;
      __hip_atomic_store(h_ex + sbase, hv, __ATOMIC_RELAXED,
                         __HIP_MEMORY_SCOPE_SYSTEM);  // fire-and-forget
    }
    sr = sw;
  }
  if (n15 < 8) {
#pragma unroll
    for (int r = 0; r < 4; ++r)
      c_gl[(bg * 16 + q * 4 + r) * 512 + myhid] = cs[r];
  }
}

// ---------------------------------------------------------------------------
// Phase 3: logits + log_softmax (reads final h slot). Unchanged from round 5.
// ---------------------------------------------------------------------------
__global__ __launch_bounds__(256) void out_kernel(
    const uint32_t* __restrict__ hfin, const float* __restrict__ Wout,
    const float* __restrict__ bout, float* __restrict__ out) {
  const int b = blockIdx.x, tid = threadIdx.x;
  __shared__ float hrow[512];
  if (tid < 64) {
    int cg = tid >> 2, w = tid & 3;
    const unsigned short* hp =
        (const unsigned short*)hfin +
        (((size_t)(b >> 4) * 16 + cg) * 4 + w) * 128 + (size_t)(b & 15) * 8;
    uint4 v = *(const uint4*)hp;
    uint32_t u[4] = {v.x, v.y, v.z, v.w};
#pragma unroll
    for (int d = 0; d < 4; ++d) {
      hrow[cg * 32 + w * 8 + d * 2] = bf2f((unsigned short)(u[d] & 0xffff));
      hrow[cg * 32 + w * 8 + d * 2 + 1] = bf2f((unsigned short)(u[d] >> 16));
    }
  }
  __syncthreads();
  float acc = bout[tid];
  for (int k = 0; k < 512; ++k) acc += hrow[k] * Wout[k * 256 + tid];
  __shared__ float red[256];
  red[tid] = acc;
  __syncthreads();
  for (int s = 128; s > 0; s >>= 1) {
    if (tid < s) red[tid] = fmaxf(red[tid], red[tid + s]);
    __syncthreads();
  }
  float mx = red[0];
  __syncthreads();
  red[tid] = __expf(acc - mx);
  __syncthreads();
  for (int s = 128; s > 0; s >>= 1) {
    if (tid < s) red[tid] += red[tid + s];
    __syncthreads();
  }
  out[b * 256 + tid] = acc - mx - logf(red[0]);
}

// ---------------------------------------------------------------------------
extern "C" void kernel_launch(void* const* d_in, const int* in_sizes, int n_in,
                              void* d_out, int out_size, void* d_ws,
                              size_t ws_size, hipStream_t stream) {
  const float* X = (const float*)d_in[0];
  const float* Wf = (const float*)d_in[1];
  const float* bf = (const float*)d_in[2];
  const float* Wi = (const float*)d_in[3];
  const float* bi = (const float*)d_in[4];
  const float* Wc = (const float*)d_in[5];
  const float* bc = (const float*)d_in[6];
  const float* Wo = (const float*)d_in[7];
  const float* bo = (const float*)d_in[8];
  const float* Wout = (const float*)d_in[9];
  const float* bout = (const float*)d_in[10];

  char* ws = (char*)d_ws;
  unsigned short* whf = (unsigned short*)(ws + 0x000000);   // 2 MiB
  unsigned short* wxb = (unsigned short*)(ws + 0x200000);   // 1 MiB
  float* bias = (float*)(ws + 0x300000);                    // 8 KiB
  float* c_gl = (float*)(ws + 0x310000);                    // 512 KiB
  uint32_t* h_ex = (uint32_t*)(ws + 0x400000);              // 257 x 256 KiB
  const size_t zoff = 0x4500000;                            // 69 MiB
  unsigned short* Z = (unsigned short*)(ws + zoff);         // TC MiB

  int TC = 256;
  while (TC > 16 && zoff + ((size_t)B_SZ * TC * 2048 * 2) > ws_size) TC >>= 1;
  int tcs = 0;
  while ((1 << tcs) < TC) ++tcs;
  const int TCp1 = TC + 1;

  pack_kernel<<<(2048 + 256 * 2048 + 1048576 + 255) / 256, 256, 0, stream>>>(
      Wf, Wi, Wc, Wo, bf, bi, bc, bo, whf, wxb, bias);
  init_kernel<<<512, 256, 0, stream>>>(h_ex, c_gl);

  for (int t0 = 0; t0 < T_SEQ; t0 += TC) {
    poison_kernel<<<(TCp1 * 16384 + 255) / 256, 256, 0, stream>>>(
        h_ex, t0 % TCp1, TCp1);
    gemm_x<<<(B_SZ * TC / 128) * 16, 256, 0, stream>>>(X, wxb, bias, Z, t0, TC,
                                                       tcs);
    lstm_chunk<<<256, 256, 0, stream>>>(Z, whf, h_ex, c_gl, t0, TC);
  }
  const int sfin = T_SEQ % TCp1;
  out_kernel<<<256, 256, 0, stream>>>(h_ex + (size_t)sfin * 65536, Wout, bout,
                                      (float*)d_out);
}